// Round 3
// baseline (1096.884 us; speedup 1.0000x reference)
//
#include <hip/hip_runtime.h>
#include <math.h>

typedef unsigned int u32;

#define BB 64
#define NN 20000
#define LL 336
#define PP 96
#define CC 16
#define DD 64
#define KC 80
#define TM 20
#define LC 5376     // L*C
#define NTAB 17
#define GH 128
#define CAP 2048    // threshold-bin candidate buffer

__constant__ int c_idmin[17] = {0,0,0,0,0,1,1,0,0,0,0,0,0,0,0,0,0};
__constant__ int c_idmax[17] = {2047,255,4095,23,6,12,53,3,1,1,15,7,2,2,2,2,1};

__device__ __forceinline__ float gelu(float x){ return 0.5f*x*(1.0f + erff(x*0.70710678118654752440f)); }
__device__ __forceinline__ float wred(float v){
  #pragma unroll
  for(int m=32;m>=1;m>>=1) v += __shfl_xor(v, m, 64);
  return v;
}
__device__ __forceinline__ u32 fkey(float f){
  u32 u = __float_as_uint(f);
  return (u & 0x80000000u) ? ~u : (u | 0x80000000u);
}

// ---------------- workspace layout (bytes), total ~105 KB ----------------
#define OFF_Q     0u            // 4096 f32
#define OFF_QN    16384u        // 4096 f32
#define OFF_XN    32768u        // 64 f32
#define OFF_CIDX  33024u        // 64*80 i32
#define OFF_METC  53504u        // 64*80 f32
#define OFF_COMB  73984u        // 64*80 f32
#define OFF_FIDX  94464u        // 64*20 i32
#define OFF_W     99584u        // 64*20 f32

// =============== 1. context encoder -> q, qn, xnorm ===============
__global__ __launch_bounds__(64) void k_ctx(
    const int* __restrict__ mids, const float* __restrict__ exo,
    const float* __restrict__ locs, const float* __restrict__ x,
    const float* __restrict__ emb,
    const float* __restrict__ cw1, const float* __restrict__ cb1,
    const float* __restrict__ cw2, const float* __restrict__ cb2,
    const float* __restrict__ ew1, const float* __restrict__ eb1,
    const float* __restrict__ ew2, const float* __restrict__ eb2,
    const float* __restrict__ lw1, const float* __restrict__ lb1,
    const float* __restrict__ lw2, const float* __restrict__ lb2,
    const float* __restrict__ lng, const float* __restrict__ lnb,
    float* __restrict__ q, float* __restrict__ qn, float* __restrict__ xn)
{
  int b = blockIdx.x, j = threadIdx.x;
  __shared__ float s_cat[272];
  __shared__ float s_h[64];
  __shared__ float s_exo[8];
  __shared__ float s_loc[12];

  for(int e=j; e<272; e+=64){
    int t=e>>4, c=e&15;
    int id = mids[b*NTAB + t];
    if(id < c_idmin[t]) id = c_idmin[t];
    if(id > c_idmax[t]) id = c_idmax[t];
    s_cat[e] = emb[((size_t)t*4096 + id)*16 + c];
  }
  if(j<8)  s_exo[j] = exo[b*8+j];
  if(j<12) s_loc[j] = locs[b*12+j];
  __syncthreads();

  // cat MLP: 272 -> 64 (gelu) -> 64
  float a = cb1[j];
  for(int i=0;i<272;i++) a += s_cat[i]*cw1[i*64+j];
  s_h[j] = gelu(a);
  __syncthreads();
  float cc = cb2[j];
  for(int k=0;k<64;k++) cc += s_h[k]*cw2[k*64+j];
  __syncthreads();

  // exo MLP: 8 -> 64 (gelu) -> 64
  a = eb1[j];
  for(int i=0;i<8;i++) a += s_exo[i]*ew1[i*64+j];
  s_h[j] = gelu(a);
  __syncthreads();
  float ec = eb2[j];
  for(int k=0;k<64;k++) ec += s_h[k]*ew2[k*64+j];
  cc += ec;
  __syncthreads();

  // loc MLP per period r: 4 -> 64 (gelu) -> 64
  float lr[3];
  for(int r=0;r<3;r++){
    a = lb1[j];
    for(int i=0;i<4;i++) a += s_loc[r*4+i]*lw1[i*64+j];
    s_h[j] = gelu(a);
    __syncthreads();
    float o = lb2[j];
    for(int k=0;k<64;k++) o += s_h[k]*lw2[k*64+j];
    lr[r] = o;
    __syncthreads();
  }

  // LayerNorm per period + mean over periods
  float g = lng[j], be = lnb[j];
  float qa = 0.f;
  for(int r=0;r<3;r++){
    float v = cc + lr[r];
    float mean = wred(v) * (1.0f/64.0f);
    float d = v - mean;
    float var = wred(d*d) * (1.0f/64.0f);
    qa += d / sqrtf(var + 1e-5f) * g + be;
  }
  float qv = qa * (1.0f/3.0f);
  q[b*64+j] = qv;
  float s2 = wred(qv*qv);
  qn[b*64+j] = qv / (sqrtf(s2) + 1e-12f);

  // ||x[b]|| over 5376 elements
  float xa = 0.f;
  for(int e=j; e<LC; e+=64){ float f = x[(size_t)b*LC+e]; xa += f*f; }
  xa = wred(xa);
  if(j==0) xn[b] = sqrtf(xa);
}

// shared sim routine: noinline so both passes emit the SAME code instance
// -> bitwise-identical values in histogram and collect passes.
__device__ __attribute__((noinline)) float row_sim(const float* pr, const float* sq)
{
  const float4* p4 = (const float4*)pr;
  float dot=0.f, ns=0.f;
  #pragma unroll
  for(int i=0;i<16;i++){
    float4 u = p4[i];
    dot += u.x*sq[i*4+0] + u.y*sq[i*4+1] + u.z*sq[i*4+2] + u.w*sq[i*4+3];
    ns  += u.x*u.x + u.y*u.y + u.z*u.z + u.w*u.w;
  }
  return dot / (sqrtf(ns) + 1e-12f);
}

// =============== 2. fused coarse sim + exact top-80 per batch row ===============
__global__ __launch_bounds__(256) void k_csel(const float* __restrict__ pc,
    const float* __restrict__ qn, int* __restrict__ cidx_out, float* __restrict__ metc)
{
  __shared__ u32 hist[4096];
  __shared__ u32 cs[256];
  __shared__ float cval[CAP];
  __shared__ int  cidxs[CAP];
  __shared__ float s_qn[64];
  __shared__ int s_T; __shared__ u32 s_above;
  __shared__ u32 s_na, s_nc;
  __shared__ float swv[4]; __shared__ int swi[4];
  int b = blockIdx.x, tid = threadIdx.x;

  for(int e=tid;e<4096;e+=256) hist[e]=0;
  if(tid<64) s_qn[tid] = qn[b*64+tid];
  if(tid==0){ s_na=0; s_nc=0; }
  // defensive prefill: any slot a later pass fails to write stays a VALID index
  for(int e=tid;e<KC;e+=256){ cidx_out[b*KC+e]=0; metc[b*KC+e]=-1.0f; }
  __syncthreads();

  // pass A: histogram of similarity keys
  for(int n=tid;n<NN;n+=256){
    float v = row_sim(pc + (size_t)n*64, s_qn);
    atomicAdd(&hist[fkey(v)>>20], 1u);
  }
  __syncthreads();
  u32 c=0;
  #pragma unroll
  for(int i=0;i<16;i++) c += hist[tid*16+i];
  cs[tid]=c;
  __syncthreads();
  if(tid==0){
    u32 acc=0, above=0; int T=0;
    for(int ch=255; ch>=0; --ch){
      if(acc + cs[ch] >= (u32)KC){
        for(int bin=ch*16+15;; --bin){
          if(acc + hist[bin] >= (u32)KC){ T=bin; above=acc; break; }
          acc += hist[bin];
        }
        break;
      }
      acc += cs[ch];
    }
    s_T = T; s_above = above;
  }
  __syncthreads();
  int T = s_T; u32 above = s_above;

  // pass B: recompute sims (identical code instance), collect
  for(int n=tid;n<NN;n+=256){
    float v = row_sim(pc + (size_t)n*64, s_qn);
    int k = (int)(fkey(v)>>20);
    if(k > T){
      u32 p = atomicAdd(&s_na,1u);
      if(p < (u32)KC){ cidx_out[b*KC+p] = n; metc[b*KC+p] = v; }
    } else if(k == T){
      u32 p = atomicAdd(&s_nc,1u);
      if(p < CAP){ cval[p]=v; cidxs[p]=n; }
    }
  }
  __syncthreads();
  int need = KC - (int)above; if(need < 0) need = 0;
  int Mc = (int)s_nc; if(Mc > CAP) Mc = CAP;
  for(int r=0;r<need;r++){
    float v=-3.0e38f; int i=-1;
    for(int e=tid;e<Mc;e+=256){ if(cval[e]>v){v=cval[e];i=e;} }
    int lane=tid&63, w=tid>>6;
    #pragma unroll
    for(int m=32;m>=1;m>>=1){
      float ov=__shfl_xor(v,m,64); int oi=__shfl_xor(i,m,64);
      if(ov>v){v=ov;i=oi;}
    }
    if(lane==0){ swv[w]=v; swi[w]=i; }
    __syncthreads();
    if(tid==0){
      float bv=swv[0]; int bi=swi[0];
      for(int k2=1;k2<4;k2++) if(swv[k2]>bv){bv=swv[k2];bi=swi[k2];}
      if(bi >= 0){
        cidx_out[b*KC+above+r] = cidxs[bi];
        metc[b*KC+above+r] = bv;
        cval[bi] = -3.0e38f;
      }
    }
    __syncthreads();
  }
}

// =============== 3. fine series sim + combined score ===============
__global__ __launch_bounds__(256) void k_fine(const float* __restrict__ px,
    const float* __restrict__ x, const int* __restrict__ cidx,
    const float* __restrict__ metc, const float* __restrict__ xn,
    float* __restrict__ comb)
{
  __shared__ float s_red[8];
  int blk = blockIdx.x;
  int b = blk / KC, k = blk % KC;
  int idx = cidx[b*KC+k];
  if(idx < 0) idx = 0;
  if(idx >= NN) idx = NN-1;   // clamp: never OOB
  const float4* pr = (const float4*)(px + (size_t)idx*LC);
  const float4* xr = (const float4*)(x + (size_t)b*LC);
  int tid = threadIdx.x;
  float dot=0.f, ns=0.f;
  for(int i=tid; i<LC/4; i+=256){   // 1344 float4 per row
    float4 a = pr[i], cx = xr[i];
    dot += cx.x*a.x + cx.y*a.y + cx.z*a.z + cx.w*a.w;
    ns  += a.x*a.x + a.y*a.y + a.z*a.z + a.w*a.w;
  }
  dot = wred(dot); ns = wred(ns);
  int lane=tid&63, w=tid>>6;
  if(lane==0){ s_red[w]=dot; s_red[4+w]=ns; }
  __syncthreads();
  if(tid==0){
    float dd = s_red[0]+s_red[1]+s_red[2]+s_red[3];
    float nn = s_red[4]+s_red[5]+s_red[6]+s_red[7];
    float s = dd / ((xn[b]+1e-12f)*(sqrtf(nn)+1e-12f));
    comb[b*KC+k] = 0.7f*metc[b*KC+k] + (1.0f-0.7f)*s;
  }
}

// =============== 4. top-20 + gate MLP + softmax weights ===============
__global__ __launch_bounds__(128) void k_gate(const float* __restrict__ comb,
    const float* __restrict__ metc, const int* __restrict__ cidx,
    const float* __restrict__ q, const float* __restrict__ pc,
    const float* __restrict__ gw1, const float* __restrict__ gb1,
    const float* __restrict__ gw2, const float* __restrict__ gb2,
    int* __restrict__ fidx, float* __restrict__ wout)
{
  __shared__ float s_w1[130*128];
  __shared__ float s_comb[80], s_met[80]; __shared__ int s_ci[80];
  __shared__ float s_q[64], s_ctx[64];
  __shared__ float selv[20], selm[20]; __shared__ int seli[20];
  __shared__ float s_gate[20];
  __shared__ float swv2[2]; __shared__ int swi2[2];
  __shared__ float s_red2[2];
  int b=blockIdx.x, tid=threadIdx.x;
  for(int e=tid;e<130*128;e+=128) s_w1[e] = gw1[e];
  if(tid<80){
    s_comb[tid]=comb[b*KC+tid]; s_met[tid]=metc[b*KC+tid];
    int ci = cidx[b*KC+tid];
    if(ci<0) ci=0;
    if(ci>=NN) ci=NN-1;            // clamp: never OOB
    s_ci[tid]=ci;
  }
  if(tid<64) s_q[tid]=q[b*64+tid];
  __syncthreads();

  // exact top-20 by combined score
  for(int r=0;r<TM;r++){
    float v=-3.0e38f; int i=-1;
    if(tid<80){ v=s_comb[tid]; i=tid; }
    int lane=tid&63, w=tid>>6;
    #pragma unroll
    for(int m=32;m>=1;m>>=1){
      float ov=__shfl_xor(v,m,64); int oi=__shfl_xor(i,m,64);
      if(ov>v){v=ov;i=oi;}
    }
    if(lane==0){ swv2[w]=v; swi2[w]=i; }
    __syncthreads();
    if(tid==0){
      float bv=swv2[0]; int bi=swi2[0];
      if(swv2[1]>bv){bv=swv2[1];bi=swi2[1];}
      if(bi<0) bi=0;
      selv[r]=bv; selm[r]=s_met[bi]; seli[r]=s_ci[bi];
      s_comb[bi]=-3.0e38f;
    }
    __syncthreads();
  }

  // gate MLP per selected candidate: [q(64)|ctx(64)|comb|meta] -> 128 gelu -> 1
  for(int m=0;m<TM;m++){
    if(tid<64) s_ctx[tid] = pc[(size_t)seli[m]*64 + tid];
    __syncthreads();
    float a = gb1[tid];
    for(int i=0;i<64;i++) a += s_q[i]  * s_w1[i*128+tid];
    for(int i=0;i<64;i++) a += s_ctx[i]* s_w1[(64+i)*128+tid];
    a += selv[m]*s_w1[128*128+tid];
    a += selm[m]*s_w1[129*128+tid];
    float h = gelu(a) * gw2[tid];
    float s = wred(h);
    int lane=tid&63, w=tid>>6;
    if(lane==0) s_red2[w]=s;
    __syncthreads();
    if(tid==0) s_gate[m] = s_red2[0]+s_red2[1]+gb2[0];
    __syncthreads();
  }

  if(tid==0){
    float lg[20]; float mx=-3.0e38f;
    for(int m=0;m<TM;m++){ lg[m] = selv[m]*10.0f + s_gate[m]; if(lg[m]>mx) mx=lg[m]; }
    float ss=0.f;
    for(int m=0;m<TM;m++){ lg[m]=expf(lg[m]-mx); ss+=lg[m]; }
    for(int m=0;m<TM;m++){ wout[b*TM+m]=lg[m]/ss; fidx[b*TM+m]=seli[m]; }
  }
}

// =============== 5. weighted sum of pool_y -> f32 output ===============
__global__ __launch_bounds__(256) void k_out(const float* __restrict__ py,
    const int* __restrict__ fidx, const float* __restrict__ wv,
    float* __restrict__ out)
{
  __shared__ float s_w[20]; __shared__ int s_i[20];
  int b=blockIdx.x, tid=threadIdx.x;
  if(tid<TM){
    s_w[tid]=wv[b*TM+tid];
    int ii=fidx[b*TM+tid];
    if(ii<0) ii=0;
    if(ii>=NN) ii=NN-1;            // clamp: never OOB
    s_i[tid]=ii;
  }
  __syncthreads();
  for(int e=tid; e<PP*CC; e+=256){   // 1536 floats per batch row
    float a0=0.f;
    #pragma unroll
    for(int m=0;m<TM;m++){
      a0 += s_w[m]*py[(size_t)s_i[m]*(PP*CC) + e];
    }
    out[(size_t)b*(PP*CC) + e] = a0;
  }
}

extern "C" void kernel_launch(void* const* d_in, const int* in_sizes, int n_in,
                              void* d_out, int out_size, void* d_ws, size_t ws_size,
                              hipStream_t stream) {
  const int*   mids = (const int*)d_in[0];
  const float* exo  = (const float*)d_in[1];
  const float* locs = (const float*)d_in[2];
  const float* x    = (const float*)d_in[3];
  const float* pc   = (const float*)d_in[4];
  const float* px   = (const float*)d_in[5];
  const float* py   = (const float*)d_in[6];
  const float* emb  = (const float*)d_in[7];
  const float* cw1  = (const float*)d_in[8];
  const float* cb1  = (const float*)d_in[9];
  const float* cw2  = (const float*)d_in[10];
  const float* cb2  = (const float*)d_in[11];
  const float* ew1  = (const float*)d_in[12];
  const float* eb1  = (const float*)d_in[13];
  const float* ew2  = (const float*)d_in[14];
  const float* eb2  = (const float*)d_in[15];
  const float* lw1  = (const float*)d_in[16];
  const float* lb1  = (const float*)d_in[17];
  const float* lw2  = (const float*)d_in[18];
  const float* lb2  = (const float*)d_in[19];
  const float* lng  = (const float*)d_in[20];
  const float* lnb  = (const float*)d_in[21];
  const float* gw1  = (const float*)d_in[22];
  const float* gb1  = (const float*)d_in[23];
  const float* gw2  = (const float*)d_in[24];
  const float* gb2  = (const float*)d_in[25];
  float* out = (float*)d_out;

  char* ws = (char*)d_ws;
  float* q    = (float*)(ws + OFF_Q);
  float* qn   = (float*)(ws + OFF_QN);
  float* xn   = (float*)(ws + OFF_XN);
  int*   cidx = (int*)  (ws + OFF_CIDX);
  float* metc = (float*)(ws + OFF_METC);
  float* comb = (float*)(ws + OFF_COMB);
  int*   fidx = (int*)  (ws + OFF_FIDX);
  float* wv   = (float*)(ws + OFF_W);

  k_ctx<<<BB, 64, 0, stream>>>(mids, exo, locs, x, emb,
      cw1, cb1, cw2, cb2, ew1, eb1, ew2, eb2,
      lw1, lb1, lw2, lb2, lng, lnb, q, qn, xn);
  k_csel<<<BB, 256, 0, stream>>>(pc, qn, cidx, metc);
  k_fine<<<BB*KC, 256, 0, stream>>>(px, x, cidx, metc, xn, comb);
  k_gate<<<BB, 128, 0, stream>>>(comb, metc, cidx, q, pc,
      gw1, gb1, gw2, gb2, fidx, wv);
  k_out<<<BB, 256, 0, stream>>>(py, fidx, wv, out);
}